// Round 3
// baseline (94.062 us; speedup 1.0000x reference)
//
#include <hip/hip_runtime.h>

// HONU order-3: out[b] = sum_{i<=j<=k} w[idx(i,j,k)] * xf[b,i]*xf[b,j]*xf[b,k]
// xf = [1, x[b,:]] (127 features). idx is closed-form (lexicographic
// combinations_with_replacement) -> comb_idx input is never read.
//
// R3: waves fully independent (1 barrier total, no atomics in main kernel).
// Task = (j, i-block-of-8); w read via wave-uniform loads (readfirstlane'd
// task id -> compiler scalarizes to s_load; w is L2-resident). Partials to
// d_ws, tiny reduce kernel finishes.

#define N_FEAT 127
#define C_TOT  349504        // Te(127)
#define IN_LEN 126
#define TILE   64            // batch rows per block (= lanes)
#define NTILES 4
#define NB     256           // blocks per tile -> 1024 blocks total (4/CU)
#define NI     8             // i-streams per task
#define NTASK  1072          // sum_j ceil((j+1)/8)
#define XPAD   127           // lane stride 127 -> 2 lanes/bank (free)
#define WPT    (NB * 4)      // waves per tile = 1024

typedef float f4 __attribute__((ext_vector_type(4), aligned(4)));

__device__ __forceinline__ int Foff(int i) {
    const int m = N_FEAT - i;
    return C_TOT - m * (m + 1) * (m + 2) / 6;
}
__device__ __forceinline__ int baseij(int i, int j) {
    return Foff(i) + (j - i) * N_FEAT - ((i + j - 1) * (j - i)) / 2;
}

__global__ __launch_bounds__(256) void honu3(
    const float* __restrict__ x, const float* __restrict__ w,
    float* __restrict__ parts)
{
    __shared__ float xS[TILE * XPAD];   // [row][feat], col 0 = bias
    const int tid  = threadIdx.x;
    const int lane = tid & 63;
    const int tile = blockIdx.y;
    const int g    = blockIdx.x;

    // ---- stage x tile (coalesced global reads) ----
    const float* xsrc = x + (size_t)tile * TILE * IN_LEN;
    for (int e = tid; e < TILE * IN_LEN; e += 256) {
        const int r = e / IN_LEN;
        const int c = e - r * IN_LEN;
        xS[r * XPAD + c + 1] = xsrc[e];
    }
    if (tid < TILE) xS[tid * XPAD] = 1.0f;
    __syncthreads();

    const int wv = __builtin_amdgcn_readfirstlane(tid >> 6);   // wave-uniform
    const float* xrow = &xS[lane * XPAD];
    float acc = 0.0f;

    // ---- independent wave tasks: t = g*4+wv, stride WPT ----
    int jcur = 0, cum = 0;
    for (int t = g * 4 + wv; t < NTASK; t += WPT) {
        int cnt = (jcur + 8) >> 3;                 // tasks at jcur
        while (cum + cnt <= t) { cum += cnt; ++jcur; cnt = (jcur + 8) >> 3; }
        const int j  = jcur;
        const int i0 = (t - cum) << 3;

        // clamped stream bases (invalid streams alias stream (j,j): masked later)
        int bq[NI];
        #pragma unroll
        for (int q = 0; q < NI; ++q)
            bq[q] = baseij(min(i0 + q, j), j);

        const int L  = N_FEAT - j;                 // k in [j, 127)
        const int KB = L >> 2;

        float d[NI];
        #pragma unroll
        for (int q = 0; q < NI; ++q) d[q] = 0.0f;

        const float* xk = xrow + j;
        #pragma unroll 2
        for (int qd = 0; qd < KB; ++qd) {
            const int kb = qd << 2;
            f4 w4[NI];
            #pragma unroll
            for (int q = 0; q < NI; ++q)
                w4[q] = *(const f4*)(w + bq[q] + kb);     // wave-uniform addr
            const float x0 = xk[kb + 0], x1 = xk[kb + 1];
            const float x2 = xk[kb + 2], x3 = xk[kb + 3];
            #pragma unroll
            for (int q = 0; q < NI; ++q) {
                d[q] = fmaf(w4[q][0], x0, d[q]);
                d[q] = fmaf(w4[q][1], x1, d[q]);
                d[q] = fmaf(w4[q][2], x2, d[q]);
                d[q] = fmaf(w4[q][3], x3, d[q]);
            }
        }
        for (int kk = KB << 2; kk < L; ++kk) {     // k tail (0-3)
            const float xv = xk[kk];
            #pragma unroll
            for (int q = 0; q < NI; ++q)
                d[q] = fmaf(w[bq[q] + kk], xv, d[q]);
        }

        // apply xf_i * xf_j; mask invalid streams via select (address clamped)
        const float xj = xrow[j];
        #pragma unroll
        for (int q = 0; q < NI; ++q) {
            const int iq = i0 + q;
            const float xv = xrow[min(iq, j)];
            const float xi = (iq <= j) ? xv : 0.0f;
            acc = fmaf(xi * xj, d[q], acc);
        }
    }

    parts[(size_t)((tile * NB + g) * 4 + wv) * 64 + lane] = acc;
}

__global__ __launch_bounds__(256) void honu3_reduce(
    const float* __restrict__ parts, float* __restrict__ out)
{
    // 32 blocks: tile = b>>3, slice of 128 waves = b&7
    const int tid  = threadIdx.x;
    const int lane = tid & 63;
    const int gg   = tid >> 6;
    const int tile = blockIdx.x >> 3;
    const int part = blockIdx.x & 7;

    const float* base = parts + (size_t)tile * WPT * 64;
    float s = 0.0f;
    #pragma unroll 8
    for (int n = 0; n < 32; ++n) {
        const int wp = part * 128 + (n << 2) + gg;   // coalesced per n
        s += base[wp * 64 + lane];
    }
    atomicAdd(&out[tile * 64 + lane], s);            // 32 adds per address
}

extern "C" void kernel_launch(void* const* d_in, const int* in_sizes, int n_in,
                              void* d_out, int out_size, void* d_ws, size_t ws_size,
                              hipStream_t stream)
{
    const float* x = (const float*)d_in[0];
    const float* w = (const float*)d_in[1];
    // d_in[2] (comb_idx) unused: index table is closed-form.
    float* out   = (float*)d_out;
    float* parts = (float*)d_ws;     // 4 * 1024 * 64 floats = 1 MB

    hipMemsetAsync(out, 0, 256 * sizeof(float), stream);
    honu3<<<dim3(NB, NTILES), 256, 0, stream>>>(x, w, parts);
    honu3_reduce<<<32, 256, 0, stream>>>(parts, out);
}

// Round 8
// 74.823 us; speedup vs baseline: 1.2571x; 1.2571x over previous
//
#include <hip/hip_runtime.h>

// HONU order-3: out[b] = sum_{i<=j<=k} w[idx(i,j,k)] * xf[b,i]*xf[b,j]*xf[b,k]
// xf = [1, x[b,:]] (127 features). idx is closed-form (lexicographic
// combinations_with_replacement) -> comb_idx input is never read.
//
// R4 (4th resubmit; rounds 4-7 all failed on GPU acquisition, never ran).
// Register-tiled VALU kernel. Lane tile = 4 rows x 4 streams (16 accs).
// Inner loop is pure ds_read_b128 + v_fmac (in-order lgkmcnt, no SMEM mix).
// Per k-quad: 8 DS instrs feed 64 FMAs. Weights staged per task with
// issue-early / write-late (vmcnt-counted loads overlap current compute).

#define N_FEAT 127
#define C_TOT  349504        // Te(127)
#define IN_LEN 126
#define NTILES 4
#define NB     192           // blocks per tile; 768 total = 3/CU (LDS-limited)
#define NTASK  568           // sum_j ceil((j+1)/16)
#define XPAD   132           // x row stride: mult-of-4 (b128 align), bank-step 4
#define WROW   132           // w row stride: same properties

typedef float f4 __attribute__((ext_vector_type(4)));

__device__ __forceinline__ int Foff(int i){ const int m = N_FEAT - i; return C_TOT - m*(m+1)*(m+2)/6; }
__device__ __forceinline__ int baseij(int i,int j){ return Foff(i) + (j-i)*N_FEAT - ((i+j-1)*(j-i))/2; }

// task t -> (j, i0): cnt(j) = ceil((j+1)/16); prefix(16a+r) = 8a(a+1) + r(a+1)
__device__ __forceinline__ void decode(int t, int& j, int& i0){
    int a = (int)((sqrtf(1.0f + 0.5f*(float)t) - 1.0f)*0.5f);
    if (a < 0) a = 0;
    while (8*(a+1)*(a+2) <= t) ++a;
    while (a > 0 && 8*a*(a+1) > t) --a;
    const int rem = t - 8*a*(a+1);
    const int ap1 = a + 1;
    int r = 0;
    while ((r+1)*ap1 <= rem) ++r;     // <=15 iters, all scalar
    j  = 16*a + r;
    i0 = (rem - r*ap1) << 4;
}

__global__ __launch_bounds__(256, 3) void honu4(
    const float* __restrict__ x, const float* __restrict__ w, float* __restrict__ out)
{
    __shared__ float smem[64*XPAD + 16*WROW];
    float* xS = smem;                   // [64][XPAD]: col0=bias, cols 127..131 = 0
    float* wb = smem + 64*XPAD;         // [16][WROW]: task weights; reused as red buf

    const int tid  = threadIdx.x;
    const int lane = tid & 63;
    const int wv   = tid >> 6;
    const int m    = lane & 15;         // row group: rows m, m+16, m+32, m+48
    const int gq   = lane >> 4;         // stream group: streams gq+4*qq
    const int tile = blockIdx.y;
    const int g    = blockIdx.x;

    // ---- stage x tile ----
    const float* xsrc = x + (size_t)tile * 64 * IN_LEN;
    for (int e = tid; e < 64*IN_LEN; e += 256){
        const int r = e / IN_LEN, c = e - r*IN_LEN;
        xS[r*XPAD + c + 1] = xsrc[e];
    }
    if (tid < 64) xS[tid*XPAD] = 1.0f;
    for (int e = tid; e < 64*5; e += 256){          // zero cols 127..131
        const int r = e/5, c = e - r*5;
        xS[r*XPAD + 127 + c] = 0.0f;
    }

    float acc[4] = {0.f, 0.f, 0.f, 0.f};

    // static mirrored task list: [0,192)+[192,384) mirrored + [384,568)
    int tl[3];
    tl[0] = g; tl[1] = 383 - g; tl[2] = 384 + g;
    const int ntl = (384 + g < NTASK) ? 3 : 2;

    const int sm4 = tid & 127;          // staging: k-offset within row
    const int ss0 = tid >> 7;           // staging: row parity (0/1)

    int pj=0, pi0=0, pk0=0, pQ=0, pnI=0;
    bool have = false;

    for (int ti = 0; ti <= ntl; ++ti) {
        // ---- issue global loads for task ti (vmcnt; overlaps compute below) ----
        float rv[8] = {0.f,0.f,0.f,0.f,0.f,0.f,0.f,0.f};
        int cj=0, ci0=0, ck0=0, cQ=0, cnI=0;
        if (ti < ntl) {
            decode(tl[ti], cj, ci0);
            ck0 = cj & ~3;
            cQ  = (N_FEAT - ck0 + 3) >> 2;          // k-quads
            cnI = min(16, cj + 1 - ci0);
            const int dj = cj - ck0;
            #pragma unroll
            for (int p = 0; p < 8; ++p) {
                const int s = ss0 + 2*p;
                if (s < cnI && sm4 >= dj && ck0 + sm4 < N_FEAT)
                    rv[p] = w[baseij(ci0 + s, cj) + (ck0 + sm4 - cj)];
            }
        }

        // ---- compute previous task (pure LDS + FMA) ----
        if (have) {
            f4 dd[4];
            #pragma unroll
            for (int qq=0; qq<4; ++qq) dd[qq] = (f4){0.f,0.f,0.f,0.f};

            for (int q8 = wv; q8 < pQ; q8 += 4) {   // waves split k-quads
                const int m4 = q8 << 2;
                f4 xq[4], wq[4];
                #pragma unroll
                for (int rr=0; rr<4; ++rr)
                    xq[rr] = *(const f4*)&xS[(m + 16*rr)*XPAD + pk0 + m4];
                #pragma unroll
                for (int qq=0; qq<4; ++qq)
                    wq[qq] = *(const f4*)&wb[(gq + 4*qq)*WROW + m4];
                #pragma unroll
                for (int qq=0; qq<4; ++qq){
                    #pragma unroll
                    for (int rr=0; rr<4; ++rr){
                        dd[qq][rr] = fmaf(wq[qq][0], xq[rr][0], dd[qq][rr]);
                        dd[qq][rr] = fmaf(wq[qq][1], xq[rr][1], dd[qq][rr]);
                        dd[qq][rr] = fmaf(wq[qq][2], xq[rr][2], dd[qq][rr]);
                        dd[qq][rr] = fmaf(wq[qq][3], xq[rr][3], dd[qq][rr]);
                    }
                }
            }
            // epilogue: acc[rr] += xj * sum_qq xi * dd  (invalid streams masked;
            // xS col>=127 is 0 so clamped reads are safe)
            #pragma unroll
            for (int rr=0; rr<4; ++rr){
                const float* xr = &xS[(m + 16*rr)*XPAD];
                const float xj = xr[pj];
                float a = 0.f;
                #pragma unroll
                for (int qq=0; qq<4; ++qq){
                    const int s = gq + 4*qq;
                    const float xi = (s < pnI) ? xr[pi0 + s] : 0.0f;
                    a = fmaf(xi, dd[qq][rr], a);
                }
                acc[rr] = fmaf(xj, a, acc[rr]);
            }
        }

        __syncthreads();                 // wb readers done
        if (ti < ntl) {
            #pragma unroll
            for (int p = 0; p < 8; ++p)
                wb[(ss0 + 2*p)*WROW + sm4] = rv[p];   // consecutive m4: conflict-free
        }
        __syncthreads();                 // wb ready

        pj=cj; pi0=ci0; pk0=ck0; pQ=cQ; pnI=cnI; have = (ti < ntl);
    }

    // ---- block reduce over (wave, stream-group), then 64 atomics/block ----
    float* red = wb;                     // safe: all wb compute done (barriered)
    *(f4*)&red[tid*4] = (f4){acc[0], acc[1], acc[2], acc[3]};
    __syncthreads();
    if (tid < 64) {
        const int mm = tid & 15, rr = tid >> 4;      // row = mm + 16*rr = tid
        float s = 0.f;
        #pragma unroll
        for (int u = 0; u < 16; ++u) {               // u = wv*4 + gq
            const int src = (u >> 2)*64 + (u & 3)*16 + mm;
            s += red[src*4 + rr];
        }
        atomicAdd(&out[tile*64 + tid], s);
    }
}

extern "C" void kernel_launch(void* const* d_in, const int* in_sizes, int n_in,
                              void* d_out, int out_size, void* d_ws, size_t ws_size,
                              hipStream_t stream)
{
    const float* x = (const float*)d_in[0];
    const float* w = (const float*)d_in[1];
    // d_in[2] (comb_idx) unused: index table is closed-form.
    float* out = (float*)d_out;

    hipMemsetAsync(out, 0, 256 * sizeof(float), stream);
    honu4<<<dim3(NB, NTILES), 256, 0, stream>>>(x, w, out);
}

// Round 11
// 74.353 us; speedup vs baseline: 1.2651x; 1.0063x over previous
//
#include <hip/hip_runtime.h>

// HONU order-3: out[b] = sum_{i<=j<=k} w[idx(i,j,k)] * xf[b,i]*xf[b,j]*xf[b,k]
// xf = [1, x[b,:]] (127 features). idx is closed-form (lexicographic
// combinations_with_replacement) -> comb_idx input is never read.
//
// R5 (2nd resubmit; acquisition timeouts, never ran).
// honu4 compute unchanged; epilogue atomics removed. 768 blocks x 64
// same-line atomicAdds (~49k on 1 KB of out) were an unmodeled ~10-15 us
// serialization tail. Now: per-block partials -> d_ws (plain coalesced
// stores), tiny no-atomic reduce kernel writes out (memset dropped too).

#define N_FEAT 127
#define C_TOT  349504        // Te(127)
#define IN_LEN 126
#define NTILES 4
#define NB     192           // blocks per tile; 768 total = 3/CU (LDS-limited)
#define NTASK  568           // sum_j ceil((j+1)/16)
#define XPAD   132           // x row stride: mult-of-4 (b128 align), bank-step 4
#define WROW   132           // w row stride: same properties

typedef float f4 __attribute__((ext_vector_type(4)));

__device__ __forceinline__ int Foff(int i){ const int m = N_FEAT - i; return C_TOT - m*(m+1)*(m+2)/6; }
__device__ __forceinline__ int baseij(int i,int j){ return Foff(i) + (j-i)*N_FEAT - ((i+j-1)*(j-i))/2; }

// task t -> (j, i0): cnt(j) = ceil((j+1)/16); prefix(16a+r) = 8a(a+1) + r(a+1)
__device__ __forceinline__ void decode(int t, int& j, int& i0){
    int a = (int)((sqrtf(1.0f + 0.5f*(float)t) - 1.0f)*0.5f);
    if (a < 0) a = 0;
    while (8*(a+1)*(a+2) <= t) ++a;
    while (a > 0 && 8*a*(a+1) > t) --a;
    const int rem = t - 8*a*(a+1);
    const int ap1 = a + 1;
    int r = 0;
    while ((r+1)*ap1 <= rem) ++r;     // <=15 iters, all scalar
    j  = 16*a + r;
    i0 = (rem - r*ap1) << 4;
}

__global__ __launch_bounds__(256, 3) void honu5(
    const float* __restrict__ x, const float* __restrict__ w, float* __restrict__ parts)
{
    __shared__ float smem[64*XPAD + 16*WROW];
    float* xS = smem;                   // [64][XPAD]: col0=bias, cols 127..131 = 0
    float* wb = smem + 64*XPAD;         // [16][WROW]: task weights; reused as red buf

    const int tid  = threadIdx.x;
    const int lane = tid & 63;
    const int wv   = tid >> 6;
    const int m    = lane & 15;         // row group: rows m, m+16, m+32, m+48
    const int gq   = lane >> 4;         // stream group: streams gq+4*qq
    const int tile = blockIdx.y;
    const int g    = blockIdx.x;

    // ---- stage x tile ----
    const float* xsrc = x + (size_t)tile * 64 * IN_LEN;
    for (int e = tid; e < 64*IN_LEN; e += 256){
        const int r = e / IN_LEN, c = e - r*IN_LEN;
        xS[r*XPAD + c + 1] = xsrc[e];
    }
    if (tid < 64) xS[tid*XPAD] = 1.0f;
    for (int e = tid; e < 64*5; e += 256){          // zero cols 127..131
        const int r = e/5, c = e - r*5;
        xS[r*XPAD + 127 + c] = 0.0f;
    }

    float acc[4] = {0.f, 0.f, 0.f, 0.f};

    // static mirrored task list: [0,192)+[192,384) mirrored + [384,568)
    int tl[3];
    tl[0] = g; tl[1] = 383 - g; tl[2] = 384 + g;
    const int ntl = (384 + g < NTASK) ? 3 : 2;

    const int sm4 = tid & 127;          // staging: k-offset within row
    const int ss0 = tid >> 7;           // staging: row parity (0/1)

    int pj=0, pi0=0, pk0=0, pQ=0, pnI=0;
    bool have = false;

    for (int ti = 0; ti <= ntl; ++ti) {
        // ---- issue global loads for task ti (vmcnt; overlaps compute below) ----
        float rv[8] = {0.f,0.f,0.f,0.f,0.f,0.f,0.f,0.f};
        int cj=0, ci0=0, ck0=0, cQ=0, cnI=0;
        if (ti < ntl) {
            decode(tl[ti], cj, ci0);
            ck0 = cj & ~3;
            cQ  = (N_FEAT - ck0 + 3) >> 2;          // k-quads
            cnI = min(16, cj + 1 - ci0);
            const int dj = cj - ck0;
            #pragma unroll
            for (int p = 0; p < 8; ++p) {
                const int s = ss0 + 2*p;
                if (s < cnI && sm4 >= dj && ck0 + sm4 < N_FEAT)
                    rv[p] = w[baseij(ci0 + s, cj) + (ck0 + sm4 - cj)];
            }
        }

        // ---- compute previous task (pure LDS + FMA) ----
        if (have) {
            f4 dd[4];
            #pragma unroll
            for (int qq=0; qq<4; ++qq) dd[qq] = (f4){0.f,0.f,0.f,0.f};

            for (int q8 = wv; q8 < pQ; q8 += 4) {   // waves split k-quads
                const int m4 = q8 << 2;
                f4 xq[4], wq[4];
                #pragma unroll
                for (int rr=0; rr<4; ++rr)
                    xq[rr] = *(const f4*)&xS[(m + 16*rr)*XPAD + pk0 + m4];
                #pragma unroll
                for (int qq=0; qq<4; ++qq)
                    wq[qq] = *(const f4*)&wb[(gq + 4*qq)*WROW + m4];
                #pragma unroll
                for (int qq=0; qq<4; ++qq){
                    #pragma unroll
                    for (int rr=0; rr<4; ++rr){
                        dd[qq][rr] = fmaf(wq[qq][0], xq[rr][0], dd[qq][rr]);
                        dd[qq][rr] = fmaf(wq[qq][1], xq[rr][1], dd[qq][rr]);
                        dd[qq][rr] = fmaf(wq[qq][2], xq[rr][2], dd[qq][rr]);
                        dd[qq][rr] = fmaf(wq[qq][3], xq[rr][3], dd[qq][rr]);
                    }
                }
            }
            // epilogue: acc[rr] += xj * sum_qq xi * dd  (invalid streams masked;
            // xS col>=127 is 0 so clamped reads are safe)
            #pragma unroll
            for (int rr=0; rr<4; ++rr){
                const float* xr = &xS[(m + 16*rr)*XPAD];
                const float xj = xr[pj];
                float a = 0.f;
                #pragma unroll
                for (int qq=0; qq<4; ++qq){
                    const int s = gq + 4*qq;
                    const float xi = (s < pnI) ? xr[pi0 + s] : 0.0f;
                    a = fmaf(xi, dd[qq][rr], a);
                }
                acc[rr] = fmaf(xj, a, acc[rr]);
            }
        }

        __syncthreads();                 // wb readers done
        if (ti < ntl) {
            #pragma unroll
            for (int p = 0; p < 8; ++p)
                wb[(ss0 + 2*p)*WROW + sm4] = rv[p];   // consecutive m4: conflict-free
        }
        __syncthreads();                 // wb ready

        pj=cj; pi0=ci0; pk0=ck0; pQ=cQ; pnI=cnI; have = (ti < ntl);
    }

    // ---- block reduce over (wave, stream-group), then plain partial store ----
    float* red = wb;                     // safe: all wb compute done (barriered)
    *(f4*)&red[tid*4] = (f4){acc[0], acc[1], acc[2], acc[3]};
    __syncthreads();
    if (tid < 64) {
        const int mm = tid & 15, rr = tid >> 4;      // row = mm + 16*rr = tid
        float s = 0.f;
        #pragma unroll
        for (int u = 0; u < 16; ++u) {               // u = wv*4 + gq
            const int src = (u >> 2)*64 + (u & 3)*16 + mm;
            s += red[src*4 + rr];
        }
        parts[((size_t)(tile * NB + g) << 6) + tid] = s;   // NO atomics
    }
}

__global__ __launch_bounds__(256) void honu5_reduce(
    const float* __restrict__ parts, float* __restrict__ out)
{
    // 4 blocks, one per tile. No atomics: each out element written once.
    const int tile = blockIdx.x;
    const int row  = threadIdx.x & 63;
    const int seg  = threadIdx.x >> 6;     // 0..3
    __shared__ float red[256];

    const float* base = parts + ((size_t)tile * NB << 6);
    float s0=0.f, s1=0.f, s2=0.f, s3=0.f;
    for (int g = seg; g < NB; g += 16) {   // 192 % 16 == 0
        s0 += base[(g     ) * 64 + row];   // coalesced per term
        s1 += base[(g +  4) * 64 + row];
        s2 += base[(g +  8) * 64 + row];
        s3 += base[(g + 12) * 64 + row];
    }
    red[threadIdx.x] = (s0 + s1) + (s2 + s3);
    __syncthreads();
    if (threadIdx.x < 64)
        out[tile * 64 + row] = (red[row] + red[64 + row]) + (red[128 + row] + red[192 + row]);
}

extern "C" void kernel_launch(void* const* d_in, const int* in_sizes, int n_in,
                              void* d_out, int out_size, void* d_ws, size_t ws_size,
                              hipStream_t stream)
{
    const float* x = (const float*)d_in[0];
    const float* w = (const float*)d_in[1];
    // d_in[2] (comb_idx) unused: index table is closed-form.
    float* out   = (float*)d_out;
    float* parts = (float*)d_ws;         // 768 * 64 floats = 196 KB, fully rewritten

    honu5<<<dim3(NB, NTILES), 256, 0, stream>>>(x, w, parts);
    honu5_reduce<<<4, 256, 0, stream>>>(parts, out);
}